// Round 8
// baseline (28.496 us; speedup 1.0000x reference)
//
#include <hip/hip_runtime.h>
#include <hip/hip_bf16.h>

#define L2E 1.4426950408889634f

// Full-rate-VALU sigmoid. Input pre-scaled: y = -log2(e) * x, returns
// sigma(x) = 1/(1 + 2^y). 14 VALU instrs, ZERO trans-pipe / ZERO LDS ops.
//   2^y: k = rint(y); f = y - k (|f| <= 0.5); 2^f by degree-4 Taylor
//        (rel err ~6e-5); scale via v_ldexp_f32.
//   1/(1+e): magic bit-trick initial guess (~5% err) + 2 Newton iters
//        (rel err ~6e-6).
// Rounds 1-7 showed the trans pipe (~24 cyc/wave64) and data-dependent LDS
// gathers (~20 cyc/wave64) are each ~10x costlier than full-rate VALU
// (2 cyc) -- every kernel using either pipe converged to 22-25 us.
__device__ __forceinline__ float sig_y(float y) {
    const float kf = __builtin_rintf(y);          // v_rndne_f32
    const float f  = y - kf;
    const int   ki = (int)kf;                     // v_cvt_i32_f32
    float p = fmaf(f, 0.009618129f, 0.055504109f);
    p = fmaf(f, p, 0.240226507f);
    p = fmaf(f, p, 0.693147181f);
    p = fmaf(f, p, 1.0f);
    const float e   = ldexpf(p, ki);              // v_ldexp_f32 (full rate)
    const float den = 1.0f + e;
    float g = __uint_as_float(0x7EF127EAu - __float_as_uint(den));
    g = g * fmaf(-den, g, 2.0f);
    g = g * fmaf(-den, g, 2.0f);
    return g;
}

__global__ __launch_bounds__(256) void lstm_fc_v8(
    const float4* __restrict__ x4,     // [B] float4 (SEQ=4, INPUT=1)
    const float*  __restrict__ W_ih,   // [8]
    const float*  __restrict__ W_hh,   // [8,2]
    const float*  __restrict__ b_ih,   // [8]
    const float*  __restrict__ b_hh,   // [8]
    const float*  __restrict__ W_fc,   // [1,2]
    const float*  __restrict__ b_fc,   // [1]
    float* __restrict__ out,           // [B]
    int B)
{
    // Pre-scaled weights (uniform -> SGPRs): y_gate = -L2E * gate for
    // sigmoid gates i,f,o; -2*L2E * gate for g (tanh(g) = 2*sigma(2g) - 1).
    // Gate order [i,f,g,o] x H=2: 0,1=i  2,3=f  4,5=g  6,7=o.
    float ws[8], w0[8], w1[8], bb[8];
#pragma unroll
    for (int g = 0; g < 8; ++g) {
        const float s = (g == 4 || g == 5) ? (-2.0f * L2E) : (-L2E);
        ws[g] = s * W_ih[g];
        w0[g] = s * W_hh[2 * g];
        w1[g] = s * W_hh[2 * g + 1];
        bb[g] = s * (b_ih[g] + b_hh[g]);
    }
    const float wfc0 = W_fc[0], wfc1 = W_fc[1], bfc = b_fc[0];
    // d-state kept pre-scaled: d = -L2E * (2c), so sigma-core(d) = sigma(2c)
    // and tanh(c) = 2*sigma(2c) - 1 directly.
    // d update: d = f*d + i * u,  u = -L2E*2*tanh(g) = 2*L2E - 4*L2E*sig2g.
    const float U_A = -4.0f * L2E, U_B = 2.0f * L2E;

    const int half = B >> 1;
    const int tid = blockIdx.x * blockDim.x + threadIdx.x;
    if (tid >= half) return;

    // Two independent elements per thread for ILP on the serial chain.
    const float4 xa = x4[tid];
    const float4 xb = x4[tid + half];
    const float xs[2][4] = {{xa.x, xa.y, xa.z, xa.w}, {xb.x, xb.y, xb.z, xb.w}};

    float h0[2], h1[2], d0[2], d1[2];

    // ---- t = 0 (h = c = 0): f unused ----
#pragma unroll
    for (int e = 0; e < 2; ++e) {
        const float xe = xs[e][0];
        const float si0 = sig_y(fmaf(ws[0], xe, bb[0]));
        const float si1 = sig_y(fmaf(ws[1], xe, bb[1]));
        const float sg0 = sig_y(fmaf(ws[4], xe, bb[4]));
        const float sg1 = sig_y(fmaf(ws[5], xe, bb[5]));
        const float so0 = sig_y(fmaf(ws[6], xe, bb[6]));
        const float so1 = sig_y(fmaf(ws[7], xe, bb[7]));
        d0[e] = si0 * fmaf(U_A, sg0, U_B);
        d1[e] = si1 * fmaf(U_A, sg1, U_B);
        const float sd0 = sig_y(d0[e]);
        const float sd1 = sig_y(d1[e]);
        const float os0 = so0 * sd0, os1 = so1 * sd1;
        h0[e] = fmaf(2.0f, os0, -so0);        // o * (2*sigma(2c) - 1)
        h1[e] = fmaf(2.0f, os1, -so1);
    }

    // ---- t = 1..3 ----
#pragma unroll
    for (int t = 1; t < 4; ++t) {
#pragma unroll
        for (int e = 0; e < 2; ++e) {
            const float xe = xs[e][t];
            float y[8];
#pragma unroll
            for (int g = 0; g < 8; ++g)
                y[g] = fmaf(ws[g], xe,
                       fmaf(w0[g], h0[e],
                       fmaf(w1[g], h1[e], bb[g])));
            const float si0 = sig_y(y[0]);
            const float si1 = sig_y(y[1]);
            const float sf0 = sig_y(y[2]);
            const float sf1 = sig_y(y[3]);
            const float sg0 = sig_y(y[4]);
            const float sg1 = sig_y(y[5]);
            const float so0 = sig_y(y[6]);
            const float so1 = sig_y(y[7]);
            d0[e] = fmaf(sf0, d0[e], si0 * fmaf(U_A, sg0, U_B));
            d1[e] = fmaf(sf1, d1[e], si1 * fmaf(U_A, sg1, U_B));
            const float sd0 = sig_y(d0[e]);
            const float sd1 = sig_y(d1[e]);
            const float os0 = so0 * sd0, os1 = so1 * sd1;
            h0[e] = fmaf(2.0f, os0, -so0);
            h1[e] = fmaf(2.0f, os1, -so1);
        }
    }

    out[tid]        = fmaf(wfc0, h0[0], fmaf(wfc1, h1[0], bfc));
    out[tid + half] = fmaf(wfc0, h0[1], fmaf(wfc1, h1[1], bfc));
}

extern "C" void kernel_launch(void* const* d_in, const int* in_sizes, int n_in,
                              void* d_out, int out_size, void* d_ws, size_t ws_size,
                              hipStream_t stream) {
    const float4* x4   = (const float4*)d_in[0];
    const float*  W_ih = (const float*)d_in[1];
    const float*  W_hh = (const float*)d_in[2];
    const float*  b_ih = (const float*)d_in[3];
    const float*  b_hh = (const float*)d_in[4];
    const float*  W_fc = (const float*)d_in[5];
    const float*  b_fc = (const float*)d_in[6];
    float* out = (float*)d_out;

    const int B = out_size;                  // 2,097,152
    const int half = B >> 1;
    const int block = 256;
    const int grid = (half + block - 1) / block;   // 4096 blocks, 2 elems/thread
    lstm_fc_v8<<<grid, block, 0, stream>>>(x4, W_ih, W_hh, b_ih, b_hh,
                                           W_fc, b_fc, out, B);
}